// Round 16
// baseline (333.799 us; speedup 1.0000x reference)
//
#include <hip/hip_runtime.h>
#include <hip/hip_bf16.h>

typedef __hip_bfloat16 bf16;
typedef __attribute__((ext_vector_type(8))) short short8;
typedef __attribute__((ext_vector_type(4))) float f32x4;
typedef __attribute__((ext_vector_type(16))) float f32x16;
typedef __attribute__((ext_vector_type(4))) int int4v;

#define S_LEN 4096
#define HID_DIM 2048

// 1/sqrt(128) * log2(e): folded into Q so softmax runs in exp2 domain
#define QSCALE ((float)(0.08838834764831845 * 1.4426950408889634))

__device__ __forceinline__ void gld_lds16(const void* g, void* l) {
  __builtin_amdgcn_global_load_lds(
      (const __attribute__((address_space(1))) void*)g,
      (__attribute__((address_space(3))) void*)l, 16, 0, 0);
}

__device__ __forceinline__ float fexp2(float x) {
  return __builtin_amdgcn_exp2f(x);  // bare v_exp_f32
}

__device__ __forceinline__ unsigned cvtpk_bf16(float lo, float hi) {
  unsigned r;
  asm("v_cvt_pk_bf16_f32 %0, %1, %2" : "=v"(r) : "v"(lo), "v"(hi));
  return r;
}

// copy-swap: x -> value held by lane's (l&31) in LOW half; y -> HIGH half's
__device__ __forceinline__ void half_swap(unsigned& x, unsigned& y) {
  asm volatile("v_permlane32_swap_b32 %0, %1" : "+v"(x), "+v"(y));
}

// ---------------- fp32 -> bf16 convert ----------------
__global__ __launch_bounds__(256) void k_cvt(const float* __restrict__ src,
                                             bf16* __restrict__ dst, int n) {
  long i = ((long)blockIdx.x * 256 + threadIdx.x) * 8;
  if (i >= n) return;
  float4 a = *reinterpret_cast<const float4*>(src + i);
  float4 b = *reinterpret_cast<const float4*>(src + i + 4);
  float v[8] = {a.x, a.y, a.z, a.w, b.x, b.y, b.z, b.w};
  short8 o;
#pragma unroll
  for (int j = 0; j < 8; ++j) {
    bf16 h = __float2bfloat16(v[j]);
    o[j] = *reinterpret_cast<short*>(&h);
  }
  *reinterpret_cast<short8*>(dst + i) = o;
}

// ------- 256^2-tile bf16 GEMM, C = A * B^T, counted-vmcnt pipeline ---------
template <typename OutT>
__global__ __launch_bounds__(512, 1) void k_gemm256(
    const bf16* __restrict__ A, const bf16* __restrict__ B,
    OutT* __restrict__ C, int M, int N, int K) {
  __shared__ bf16 Al[2][256 * 64];   // 64 KB
  __shared__ bf16 Bl[2][256 * 64];   // 64 KB
  const int tid = threadIdx.x;
  const int lane = tid & 63;
  const int wid = tid >> 6;
  const int wr = wid >> 2;
  const int wc = wid & 3;
  const long brow = (long)blockIdx.y * 256;
  const long bcol = (long)blockIdx.x * 256;
  const int NT = K >> 6;

  auto stage = [&](int kt, int buf) {
    const bf16* At = A + brow * K + kt * 64;
    const bf16* Bt = B + bcol * K + kt * 64;
#pragma unroll
    for (int i = 0; i < 4; ++i) {
      const int ch = tid + i * 512;
      const int row = ch >> 3;
      const int j = (ch & 7) ^ (row & 7);
      gld_lds16(At + (size_t)row * K + j * 8, &Al[buf][(wid * 64 + i * 512) * 8]);
    }
#pragma unroll
    for (int i = 0; i < 4; ++i) {
      const int ch = tid + i * 512;
      const int row = ch >> 3;
      const int j = (ch & 7) ^ (row & 7);
      gld_lds16(Bt + (size_t)row * K + j * 8, &Bl[buf][(wid * 64 + i * 512) * 8]);
    }
  };

  f32x4 acc0[4][4], acc1[4][4];
#pragma unroll
  for (int m = 0; m < 4; ++m)
#pragma unroll
    for (int n = 0; n < 4; ++n) {
      acc0[m][n] = (f32x4){0.f, 0.f, 0.f, 0.f};
      acc1[m][n] = (f32x4){0.f, 0.f, 0.f, 0.f};
    }

  const int l15 = lane & 15;
  const int cp0 = ((lane >> 4) ^ (lane & 7)) * 8;
  const int cp1 = ((4 + (lane >> 4)) ^ (lane & 7)) * 8;

  stage(0, 0);
  stage(1, 1);
  asm volatile("s_waitcnt vmcnt(8)" ::: "memory");
  __builtin_amdgcn_s_barrier();

  for (int kt = 0; kt < NT; ++kt) {
    const bf16* Ab = &Al[kt & 1][0];
    const bf16* Bb = &Bl[kt & 1][0];
    short8 bB[4][2], aA[4][2];
#pragma unroll
    for (int n = 0; n < 4; ++n) {
      const int rb = (wc * 64 + n * 16 + l15) * 64;
      bB[n][0] = *reinterpret_cast<const short8*>(&Bb[rb + cp0]);
      bB[n][1] = *reinterpret_cast<const short8*>(&Bb[rb + cp1]);
    }
#pragma unroll
    for (int m = 0; m < 4; ++m) {
      const int ra = (wr * 128 + m * 16 + l15) * 64;
      aA[m][0] = *reinterpret_cast<const short8*>(&Ab[ra + cp0]);
      aA[m][1] = *reinterpret_cast<const short8*>(&Ab[ra + cp1]);
    }
    __builtin_amdgcn_s_setprio(1);
#pragma unroll
    for (int m = 0; m < 4; ++m)
#pragma unroll
      for (int n = 0; n < 4; ++n) {
        acc0[m][n] = __builtin_amdgcn_mfma_f32_16x16x32_bf16(aA[m][0], bB[n][0],
                                                             acc0[m][n], 0, 0, 0);
        acc0[m][n] = __builtin_amdgcn_mfma_f32_16x16x32_bf16(aA[m][1], bB[n][1],
                                                             acc0[m][n], 0, 0, 0);
      }
    __builtin_amdgcn_s_setprio(0);
#pragma unroll
    for (int m = 0; m < 4; ++m) {
      const int ra = (wr * 128 + 64 + m * 16 + l15) * 64;
      aA[m][0] = *reinterpret_cast<const short8*>(&Ab[ra + cp0]);
      aA[m][1] = *reinterpret_cast<const short8*>(&Ab[ra + cp1]);
    }
    __builtin_amdgcn_s_setprio(1);
#pragma unroll
    for (int m = 0; m < 4; ++m)
#pragma unroll
      for (int n = 0; n < 4; ++n) {
        acc1[m][n] = __builtin_amdgcn_mfma_f32_16x16x32_bf16(aA[m][0], bB[n][0],
                                                             acc1[m][n], 0, 0, 0);
        acc1[m][n] = __builtin_amdgcn_mfma_f32_16x16x32_bf16(aA[m][1], bB[n][1],
                                                             acc1[m][n], 0, 0, 0);
      }
    __builtin_amdgcn_s_setprio(0);

    if (kt + 1 < NT) {
      __builtin_amdgcn_s_barrier();
      if (kt + 2 < NT) {
        stage(kt + 2, kt & 1);
        asm volatile("s_waitcnt vmcnt(8)" ::: "memory");
      } else {
        asm volatile("s_waitcnt vmcnt(0)" ::: "memory");
      }
      __builtin_amdgcn_s_barrier();
    }
  }

#pragma unroll
  for (int mh = 0; mh < 2; ++mh) {
#pragma unroll
    for (int m = 0; m < 4; ++m) {
      const long r0 = brow + wr * 128 + mh * 64 + m * 16 + (lane >> 4) * 4;
#pragma unroll
      for (int n = 0; n < 4; ++n) {
        const long c0 = bcol + wc * 64 + n * 16 + l15;
        const f32x4 v = mh ? acc1[m][n] : acc0[m][n];
#pragma unroll
        for (int r = 0; r < 4; ++r) {
          if constexpr (sizeof(OutT) == 2)
            C[(r0 + r) * N + c0] = __float2bfloat16(v[r]);
          else
            C[(r0 + r) * N + c0] = v[r];
        }
      }
    }
  }
}

// ------- 256x128-tile bf16 GEMM (out-proj), counted-vmcnt pipeline ---------
__global__ __launch_bounds__(512, 1) void k_gemm_op(
    const bf16* __restrict__ A, const bf16* __restrict__ B,
    float* __restrict__ C, int M, int N, int K) {
  __shared__ bf16 Al[2][256 * 64];   // 64 KB
  __shared__ bf16 Bl[2][128 * 64];   // 32 KB
  const int tid = threadIdx.x;
  const int lane = tid & 63;
  const int wid = tid >> 6;
  const int wr = wid >> 1;
  const int wc = wid & 1;
  const long brow = (long)blockIdx.y * 256;
  const long bcol = (long)blockIdx.x * 128;
  const int NT = K >> 6;

  auto stage = [&](int kt, int buf) {
    const bf16* At = A + brow * K + kt * 64;
    const bf16* Bt = B + bcol * K + kt * 64;
#pragma unroll
    for (int i = 0; i < 4; ++i) {
      const int ch = tid + i * 512;
      const int row = ch >> 3;
      const int j = (ch & 7) ^ (row & 7);
      gld_lds16(At + (size_t)row * K + j * 8, &Al[buf][(wid * 64 + i * 512) * 8]);
    }
#pragma unroll
    for (int i = 0; i < 2; ++i) {
      const int ch = tid + i * 512;
      const int row = ch >> 3;
      const int j = (ch & 7) ^ (row & 7);
      gld_lds16(Bt + (size_t)row * K + j * 8, &Bl[buf][(wid * 64 + i * 512) * 8]);
    }
  };

  f32x4 acc[4][4];
#pragma unroll
  for (int m = 0; m < 4; ++m)
#pragma unroll
    for (int n = 0; n < 4; ++n) acc[m][n] = (f32x4){0.f, 0.f, 0.f, 0.f};

  const int l15 = lane & 15;
  const int cp0 = ((lane >> 4) ^ (lane & 7)) * 8;
  const int cp1 = ((4 + (lane >> 4)) ^ (lane & 7)) * 8;

  stage(0, 0);
  stage(1, 1);
  asm volatile("s_waitcnt vmcnt(6)" ::: "memory");
  __builtin_amdgcn_s_barrier();

  for (int kt = 0; kt < NT; ++kt) {
    const bf16* Ab = &Al[kt & 1][0];
    const bf16* Bb = &Bl[kt & 1][0];
    short8 bB[4][2], aA[4][2];
#pragma unroll
    for (int n = 0; n < 4; ++n) {
      const int rb = (wc * 64 + n * 16 + l15) * 64;
      bB[n][0] = *reinterpret_cast<const short8*>(&Bb[rb + cp0]);
      bB[n][1] = *reinterpret_cast<const short8*>(&Bb[rb + cp1]);
    }
#pragma unroll
    for (int m = 0; m < 4; ++m) {
      const int ra = (wr * 64 + m * 16 + l15) * 64;
      aA[m][0] = *reinterpret_cast<const short8*>(&Ab[ra + cp0]);
      aA[m][1] = *reinterpret_cast<const short8*>(&Ab[ra + cp1]);
    }
    __builtin_amdgcn_s_setprio(1);
#pragma unroll
    for (int m = 0; m < 4; ++m)
#pragma unroll
      for (int n = 0; n < 4; ++n) {
        acc[m][n] = __builtin_amdgcn_mfma_f32_16x16x32_bf16(aA[m][0], bB[n][0],
                                                            acc[m][n], 0, 0, 0);
        acc[m][n] = __builtin_amdgcn_mfma_f32_16x16x32_bf16(aA[m][1], bB[n][1],
                                                            acc[m][n], 0, 0, 0);
      }
    __builtin_amdgcn_s_setprio(0);

    if (kt + 1 < NT) {
      __builtin_amdgcn_s_barrier();
      if (kt + 2 < NT) {
        stage(kt + 2, kt & 1);
        asm volatile("s_waitcnt vmcnt(6)" ::: "memory");
      } else {
        asm volatile("s_waitcnt vmcnt(0)" ::: "memory");
      }
      __builtin_amdgcn_s_barrier();
    }
  }

#pragma unroll
  for (int m = 0; m < 4; ++m) {
    const long r0 = brow + wr * 64 + m * 16 + (lane >> 4) * 4;
#pragma unroll
    for (int n = 0; n < 4; ++n) {
      const long c0 = bcol + wc * 64 + n * 16 + l15;
#pragma unroll
      for (int r = 0; r < 4; ++r) C[(r0 + r) * N + c0] = acc[m][n][r];
    }
  }
}

// ---------------- RMSNorm + RoPE + layout for attention ----------------
__global__ __launch_bounds__(256) void k_normrope(
    const bf16* __restrict__ QKVb, const float* __restrict__ cosb,
    const float* __restrict__ sinb, const float* __restrict__ qw,
    const float* __restrict__ kw, bf16* __restrict__ Qb, bf16* __restrict__ Kb,
    bf16* __restrict__ Vb) {
  const int lane = threadIdx.x & 63;
  const int row = blockIdx.x * 4 + (threadIdx.x >> 6);
  const int s = row >> 5;
  const int idx = row & 31;
  const bf16* src = QKVb + (size_t)s * 4096 + idx * 128;
  float x0 = __bfloat162float(src[lane]);
  float x1 = __bfloat162float(src[lane + 64]);
  if (idx < 24) {
    float ss = x0 * x0 + x1 * x1;
#pragma unroll
    for (int off = 1; off < 64; off <<= 1) ss += __shfl_xor(ss, off);
    const float rn = rsqrtf(ss * (1.f / 128.f) + 1e-6f);
    const float* w = (idx < 16) ? qw : kw;
    x0 = x0 * rn * w[lane];
    x1 = x1 * rn * w[lane + 64];
    const float c0 = cosb[(size_t)s * 128 + lane];
    const float c1 = cosb[(size_t)s * 128 + lane + 64];
    const float s0 = sinb[(size_t)s * 128 + lane];
    const float s1 = sinb[(size_t)s * 128 + lane + 64];
    float o0 = x0 * c0 - x1 * s0;
    float o1 = x1 * c1 + x0 * s1;
    if (idx < 16) { o0 *= QSCALE; o1 *= QSCALE; }
    bf16* dst = (idx < 16) ? (Qb + ((size_t)idx * S_LEN + s) * 128)
                           : (Kb + ((size_t)(idx - 16) * S_LEN + s) * 128);
    dst[lane] = __float2bfloat16(o0);
    dst[lane + 64] = __float2bfloat16(o1);
  } else {
    bf16* dst = Vb + ((size_t)(idx - 24) * S_LEN + s) * 128;
    dst[lane] = __float2bfloat16(x0);
    dst[lane + 64] = __float2bfloat16(x1);
  }
}

// ---------------- V transpose: Vb [KV][S][128] -> Vt [KV][128][S] ----------
__global__ __launch_bounds__(256) void k_vt(const bf16* __restrict__ Vb,
                                            bf16* __restrict__ Vt) {
  __shared__ bf16 Lds[64][136];
  const int tid = threadIdx.x;
  const int s0 = blockIdx.x * 64;
  const int kv = blockIdx.y;
#pragma unroll
  for (int pass = 0; pass < 4; ++pass) {
    const int c = tid + pass * 256;
    const int r = c >> 4;
    const int off = (c & 15) * 8;
    *reinterpret_cast<short8*>(&Lds[r][off]) =
        *reinterpret_cast<const short8*>(
            &Vb[((size_t)kv * S_LEN + s0 + r) * 128 + off]);
  }
  __syncthreads();
#pragma unroll
  for (int pass = 0; pass < 4; ++pass) {
    const int c = tid + pass * 256;
    const int d = c >> 3;
    const int so = (c & 7) * 8;
    short8 o;
#pragma unroll
    for (int j = 0; j < 8; ++j) {
      bf16 e = Lds[so + j][d];
      o[j] = *reinterpret_cast<short*>(&e);
    }
    *reinterpret_cast<short8*>(&Vt[((size_t)kv * 128 + d) * S_LEN + s0 + so]) = o;
  }
}

// ----- causal flash attention, 32x32 MFMA + split-KV (GQA 16q/8kv, D=128) ---
// 256 threads, 4 waves x 32 q = 128 q/block. grid (32, H): bx = pr*2 + part;
// block does jobs (g=pr, part), (g=31-pr, part); each job has g+1 tiles ->
// uniform 33 tiles. Swapped QK^T (lane owns q = lane&31); P in-register via
// cvt_pk + permlane32_swap (no P LDS). Writes unnormalized O + m,l; merged.
__global__ __launch_bounds__(256) void k_attn_part(
    const bf16* __restrict__ Qb, const bf16* __restrict__ Kb,
    const bf16* __restrict__ Vt_g, float* __restrict__ Opart,
    float* __restrict__ ML) {
  __shared__ bf16 Kl[2][64 * 128];   // [kv][d], swizzled, 32 KB
  __shared__ bf16 Vl[2][128 * 64];   // [d][kv], swizzled, 32 KB
  const int tid = threadIdx.x;
  const int lane = tid & 63;
  const int wv = tid >> 6;
  const int h = blockIdx.y;
  const int kvh = h >> 1;
  const int pr = blockIdx.x >> 1;
  const int part = blockIdx.x & 1;
  const int q32 = lane & 31;
  const int hh = lane >> 5;          // k-slice half

  const bf16* Kbase = Kb + (size_t)kvh * S_LEN * 128;
  const bf16* Vbase = Vt_g + (size_t)kvh * 128 * S_LEN;

  // stage: linear LDS dest, inverse-swizzled global src (rule 21).
  // K swizzle f(j,row) = (j&8) | ((((j&7)^(row&7)) + 2*((row>>3)&3)) & 7)
  // V swizzle g(j,d)   = (((j^(d&7)) + 2*((d>>3)&3)) & 7)
  auto stage = [&](int t, int buf) {
    const bf16* Kt = Kbase + (size_t)t * 64 * 128;
    const bf16* Vt = Vbase + t * 64;
#pragma unroll
    for (int p = 0; p < 4; ++p) {
      const int ch = tid + p * 256;
      const int row = ch >> 4, cpos = ch & 15;
      const int j = (cpos & 8) |
                    ((((cpos & 7) - 2 * ((row >> 3) & 3)) & 7) ^ (row & 7));
      gld_lds16(Kt + row * 128 + j * 8, &Kl[buf][(wv * 64 + p * 256) * 8]);
    }
#pragma unroll
    for (int p = 0; p < 4; ++p) {
      const int ch = tid + p * 256;
      const int d = ch >> 3, cpos = ch & 7;
      const int j = (((cpos - 2 * ((d >> 3) & 3)) & 7)) ^ (d & 7);
      gld_lds16(Vt + (size_t)d * S_LEN + j * 8, &Vl[buf][(wv * 64 + p * 256) * 8]);
    }
  };

  for (int hf = 0; hf < 2; ++hf) {
    const int g = hf ? (31 - pr) : pr;
    const int qrow = g * 128 + wv * 32;
    const int grow = qrow + q32;         // this lane's global q row
    const int t0 = part ? (g + 1) : 0;
    const int t1 = part ? (2 * g + 2) : (g + 1);
    const int diag = 2 * g + (wv >> 1);  // this wave's diagonal tile

    if (hf) __syncthreads();
    stage(t0, 0);

    // Q as B-operand: lane holds col q=q32, k = ks*16 + hh*8 + j
    short8 qf[8];
    {
      const bf16* qp = Qb + ((size_t)h * S_LEN + grow) * 128 + hh * 8;
#pragma unroll
      for (int ks = 0; ks < 8; ++ks)
        qf[ks] = *reinterpret_cast<const short8*>(qp + ks * 16);
    }

    f32x16 oacc[4];
#pragma unroll
    for (int i = 0; i < 4; ++i)
#pragma unroll
      for (int r = 0; r < 16; ++r) oacc[i][r] = 0.f;
    float m_run = -1e30f;
    float l_part = 0.f;

    auto tile = [&](int t, int buf, bool mask) {
      // S^T = K Q^T (32x32x16): sacc[nt] reg r -> kv = t*64 + nt*32 +
      // (r&3) + 8*(r>>2) + 4*hh, q = q32
      f32x16 sacc[2];
#pragma unroll
      for (int nt = 0; nt < 2; ++nt)
#pragma unroll
        for (int r = 0; r < 16; ++r) sacc[nt][r] = 0.f;
#pragma unroll
      for (int ks = 0; ks < 8; ++ks) {
#pragma unroll
        for (int nt = 0; nt < 2; ++nt) {
          const int row = nt * 32 + q32;
          const int ck = 2 * ks + hh;
          const int cpos = (ck & 8) |
                           ((((ck & 7) ^ (row & 7)) + 2 * ((row >> 3) & 3)) & 7);
          short8 kf =
              *reinterpret_cast<const short8*>(&Kl[buf][row * 128 + cpos * 8]);
          sacc[nt] = __builtin_amdgcn_mfma_f32_32x32x16_bf16(kf, qf[ks],
                                                             sacc[nt], 0, 0, 0);
        }
      }

      // lane-local softmax (q = q32); kv split across lane^32
      float tm = -1e30f;
#pragma unroll
      for (int nt = 0; nt < 2; ++nt)
#pragma unroll
        for (int r = 0; r < 16; ++r) {
          float sv = sacc[nt][r];
          if (mask) {
            const int kv = t * 64 + nt * 32 + (r & 3) + 8 * (r >> 2) + 4 * hh;
            if (kv > grow) sv = -1e30f;
          }
          sacc[nt][r] = sv;
          tm = fmaxf(tm, sv);
        }
      tm = fmaxf(tm, __shfl_xor(tm, 32));
      if (__any(tm > m_run + 8.f)) {
        const float mn = fmaxf(m_run, tm);
        const float alpha = fexp2(m_run - mn);
        m_run = mn;
        l_part *= alpha;
#pragma unroll
        for (int dn = 0; dn < 4; ++dn)
#pragma unroll
          for (int r = 0; r < 16; ++r) oacc[dn][r] *= alpha;
      }
#pragma unroll
      for (int nt = 0; nt < 2; ++nt)
#pragma unroll
        for (int r = 0; r < 16; ++r) {
          const float p = fexp2(sacc[nt][r] - m_run);
          sacc[nt][r] = p;
          l_part += p;
        }

      // O^T += V^T P^T (32x32x16); P assembled in-register per kstep
#pragma unroll
      for (int ks = 0; ks < 4; ++ks) {
        const int nt = ks >> 1;
        const int b0 = 2 * (ks & 1);
        // pack own words for b = b0, b0+1 (kv = 8b + 4*hh + {0..3})
        unsigned a00 = cvtpk_bf16(sacc[nt][4 * b0 + 0], sacc[nt][4 * b0 + 1]);
        unsigned a01 = cvtpk_bf16(sacc[nt][4 * b0 + 2], sacc[nt][4 * b0 + 3]);
        unsigned a10 = cvtpk_bf16(sacc[nt][4 * b0 + 4], sacc[nt][4 * b0 + 5]);
        unsigned a11 = cvtpk_bf16(sacc[nt][4 * b0 + 6], sacc[nt][4 * b0 + 7]);
        unsigned x00 = a00, y00 = a00; half_swap(x00, y00);
        unsigned x01 = a01, y01 = a01; half_swap(x01, y01);
        unsigned x10 = a10, y10 = a10; half_swap(x10, y10);
        unsigned x11 = a11, y11 = a11; half_swap(x11, y11);
        // B-frag: k = ks*16 + hh*8 + j; select b' = b0 + hh
        int4v pw;
        pw[0] = (int)(hh ? x10 : x00);
        pw[1] = (int)(hh ? x11 : x01);
        pw[2] = (int)(hh ? y10 : y00);
        pw[3] = (int)(hh ? y11 : y01);
        const short8 pf = __builtin_bit_cast(short8, pw);
#pragma unroll
        for (int dn = 0; dn < 4; ++dn) {
          const int d = dn * 32 + q32;
          const int cv = 2 * ks + hh;
          const int cpos = (((cv ^ (d & 7)) + 2 * ((d >> 3) & 3)) & 7);
          short8 vf =
              *reinterpret_cast<const short8*>(&Vl[buf][d * 64 + cpos * 8]);
          oacc[dn] = __builtin_amdgcn_mfma_f32_32x32x16_bf16(vf, pf, oacc[dn],
                                                             0, 0, 0);
        }
      }
    };

    __syncthreads();  // tile t0 staged
    int cur = 0;
    for (int t = t0; t < t1 - 1; ++t) {
      stage(t + 1, cur ^ 1);
      if (t <= diag) tile(t, cur, t == diag);
      __syncthreads();
      cur ^= 1;
    }
    if (t1 - 1 <= diag) tile(t1 - 1, cur, (t1 - 1) == diag);

    // epilogue: unnormalized partial O (f32) + m, l
    float lt = l_part + __shfl_xor(l_part, 32);
    const int job = (h * 32 + g) * 2 + part;
    float* Op = Opart + (size_t)job * 128 * 128;
    float* MLp = ML + (size_t)job * 256;
    const int rq = wv * 32 + q32;
#pragma unroll
    for (int dn = 0; dn < 4; ++dn)
#pragma unroll
      for (int b = 0; b < 4; ++b) {
        float4 v;
        v.x = oacc[dn][4 * b + 0];
        v.y = oacc[dn][4 * b + 1];
        v.z = oacc[dn][4 * b + 2];
        v.w = oacc[dn][4 * b + 3];
        *reinterpret_cast<float4*>(&Op[rq * 128 + dn * 32 + 8 * b + 4 * hh]) = v;
      }
    if (lane < 32) {
      MLp[rq] = m_run;
      MLp[128 + rq] = lt;
    }
  }
}

// ---------------- merge split-KV partials -> AO bf16 [S][H*D] --------------
__global__ __launch_bounds__(256) void k_merge(const float* __restrict__ Opart,
                                               const float* __restrict__ ML,
                                               bf16* __restrict__ AO) {
  const int idx = blockIdx.x * 4 + (threadIdx.x >> 6);  // h*4096 + s
  const int lane = threadIdx.x & 63;
  const int h = idx >> 12;
  const int s = idx & 4095;
  const int g = s >> 7, rowin = s & 127;
  const int j0 = (h * 32 + g) * 2;
  const float m0 = ML[(size_t)j0 * 256 + rowin];
  const float l0 = ML[(size_t)j0 * 256 + 128 + rowin];
  const float m1 = ML[(size_t)(j0 + 1) * 256 + rowin];
  const float l1 = ML[(size_t)(j0 + 1) * 256 + 128 + rowin];
  const float mm = fmaxf(m0, m1);
  const float a0 = fexp2(m0 - mm), a1 = fexp2(m1 - mm);
  const float inv = 1.f / (l0 * a0 + l1 * a1);
  const float2 o0 = *reinterpret_cast<const float2*>(
      &Opart[((size_t)j0 * 128 + rowin) * 128 + lane * 2]);
  const float2 o1 = *reinterpret_cast<const float2*>(
      &Opart[((size_t)(j0 + 1) * 128 + rowin) * 128 + lane * 2]);
  bf16* dst = AO + (size_t)s * HID_DIM + h * 128 + lane * 2;
  dst[0] = __float2bfloat16((o0.x * a0 + o1.x * a1) * inv);
  dst[1] = __float2bfloat16((o0.y * a0 + o1.y * a1) * inv);
}

extern "C" void kernel_launch(void* const* d_in, const int* in_sizes, int n_in,
                              void* d_out, int out_size, void* d_ws,
                              size_t ws_size, hipStream_t stream) {
  (void)in_sizes; (void)n_in; (void)out_size; (void)ws_size;
  const float* hs = (const float*)d_in[0];
  const float* cosb = (const float*)d_in[1];
  const float* sinb = (const float*)d_in[2];
  const float* wq = (const float*)d_in[3];
  const float* wk = (const float*)d_in[4];
  const float* wv = (const float*)d_in[5];
  const float* wo = (const float*)d_in[6];
  const float* qnw = (const float*)d_in[7];
  const float* knw = (const float*)d_in[8];
  float* out = (float*)d_out;
  char* ws = (char*)d_ws;

  // workspace layout (bytes); Opart/ML overlay buffers dead by attn time
  bf16* Ah = (bf16*)(ws + 0);              // hidden bf16        16.78 MB
  bf16* Wqkv = (bf16*)(ws + 16777216);     // packed qkv weights 16.78 MB
  bf16* QKVb = (bf16*)(ws + 33554432);     // qkv proj bf16      33.55 MB
  bf16* Qb = (bf16*)(ws + 67108864);       // Q [H][S][D]        16.78 MB
  bf16* Kb = (bf16*)(ws + 83886080);       // K [KV][S][D]        8.39 MB
  bf16* Vb = (bf16*)(ws + 92274688);       // V [KV][S][D]        8.39 MB
  bf16* Vt = (bf16*)(ws + 100663296);      // V^T [KV][128][S]    8.39 MB
  bf16* AO = (bf16*)(ws + 109051904);      // attn out [S][H*D]  16.78 MB
  bf16* Wo = (bf16*)(ws + 125829120);      // wo bf16             8.39 MB
  float* Opart = (float*)(ws + 0);         // overlay Ah..QKVb   67.11 MB
  float* ML = (float*)(ws + 92274688);     // overlay Vb          1.05 MB

  auto cvt = [&](const float* s, bf16* d, long n) {
    k_cvt<<<dim3((unsigned)((n / 8 + 255) / 256)), dim3(256), 0, stream>>>(
        s, d, (int)n);
  };
  cvt(hs, Ah, (long)S_LEN * HID_DIM);
  cvt(wq, Wqkv, (long)2048 * 2048);
  cvt(wk, Wqkv + (long)2048 * 2048, (long)1024 * 2048);
  cvt(wv, Wqkv + (long)3072 * 2048, (long)1024 * 2048);
  cvt(wo, Wo, (long)2048 * 2048);

  k_gemm256<bf16><<<dim3(16, 16), dim3(512), 0, stream>>>(Ah, Wqkv, QKVb, 4096,
                                                          4096, 2048);
  k_normrope<<<dim3(32768), dim3(256), 0, stream>>>(QKVb, cosb, sinb, qnw, knw,
                                                    Qb, Kb, Vb);
  k_vt<<<dim3(64, 8), dim3(256), 0, stream>>>(Vb, Vt);
  k_attn_part<<<dim3(32, 16), dim3(256), 0, stream>>>(Qb, Kb, Vt, Opart, ML);
  k_merge<<<dim3(16384), dim3(256), 0, stream>>>(Opart, ML, AO);
  k_gemm_op<<<dim3(16, 16), dim3(512), 0, stream>>>(AO, Wo, out, 4096, 2048,
                                                    2048);
}

// Round 17
// 275.742 us; speedup vs baseline: 1.2105x; 1.2105x over previous
//
#include <hip/hip_runtime.h>
#include <hip/hip_bf16.h>

typedef __hip_bfloat16 bf16;
typedef __attribute__((ext_vector_type(8))) short short8;
typedef __attribute__((ext_vector_type(4))) float f32x4;

#define S_LEN 4096
#define HID_DIM 2048

// 1/sqrt(128) * log2(e): folded into Q so softmax runs in exp2 domain
#define QSCALE ((float)(0.08838834764831845 * 1.4426950408889634))

__device__ __forceinline__ void gld_lds16(const void* g, void* l) {
  __builtin_amdgcn_global_load_lds(
      (const __attribute__((address_space(1))) void*)g,
      (__attribute__((address_space(3))) void*)l, 16, 0, 0);
}

__device__ __forceinline__ float fexp2(float x) {
  return __builtin_amdgcn_exp2f(x);  // bare v_exp_f32
}

__device__ __forceinline__ unsigned cvtpk_bf16(float lo, float hi) {
  unsigned r;
  asm("v_cvt_pk_bf16_f32 %0, %1, %2" : "=v"(r) : "v"(lo), "v"(hi));
  return r;
}

// ---------------- fused fp32 -> bf16 convert (all 5 tensors) ----------------
// seg sizes in 8-elem units: hs 1048576 | wq 524288 | wk 262144 | wv 262144
// | wo 524288 ; total 2621440 units -> 10240 blocks x 256 thr
__global__ __launch_bounds__(256) void k_cvt5(
    const float* __restrict__ hs, const float* __restrict__ wq,
    const float* __restrict__ wk, const float* __restrict__ wv,
    const float* __restrict__ wo, bf16* __restrict__ Ah,
    bf16* __restrict__ Wqkv, bf16* __restrict__ Wo) {
  long u = (long)blockIdx.x * 256 + threadIdx.x;  // 8-elem unit index
  const float* src;
  bf16* dst;
  if (u < 1048576) {
    src = hs; dst = Ah;
  } else if (u < 1572864) {
    u -= 1048576; src = wq; dst = Wqkv;
  } else if (u < 1835008) {
    u -= 1572864; src = wk; dst = Wqkv + (long)2048 * 2048;
  } else if (u < 2097152) {
    u -= 1835008; src = wv; dst = Wqkv + (long)3072 * 2048;
  } else {
    u -= 2097152; src = wo; dst = Wo;
  }
  const long i = u * 8;
  float4 a = *reinterpret_cast<const float4*>(src + i);
  float4 b = *reinterpret_cast<const float4*>(src + i + 4);
  float v[8] = {a.x, a.y, a.z, a.w, b.x, b.y, b.z, b.w};
  short8 o;
#pragma unroll
  for (int j = 0; j < 8; ++j) {
    bf16 h = __float2bfloat16(v[j]);
    o[j] = *reinterpret_cast<short*>(&h);
  }
  *reinterpret_cast<short8*>(dst + i) = o;
}

// bijective XCD swizzle for nwg % 8 == 0 (T1, m204)
__device__ __forceinline__ int2 xcd_swz(int nx) {
  const int bid = blockIdx.y * nx + blockIdx.x;
  const int nwg = nx * gridDim.y;
  const int q = nwg >> 3;
  const int swz = (bid & 7) * q + (bid >> 3);
  return make_int2(swz % nx, swz / nx);
}

// ------- 256^2-tile bf16 GEMM, C = A * B^T, counted-vmcnt pipeline ---------
template <typename OutT>
__global__ __launch_bounds__(512, 1) void k_gemm256(
    const bf16* __restrict__ A, const bf16* __restrict__ B,
    OutT* __restrict__ C, int M, int N, int K) {
  __shared__ bf16 Al[2][256 * 64];   // 64 KB
  __shared__ bf16 Bl[2][256 * 64];   // 64 KB
  const int tid = threadIdx.x;
  const int lane = tid & 63;
  const int wid = tid >> 6;
  const int wr = wid >> 2;
  const int wc = wid & 3;
  const int2 bxy = xcd_swz(gridDim.x);
  const long brow = (long)bxy.y * 256;
  const long bcol = (long)bxy.x * 256;
  const int NT = K >> 6;

  auto stage = [&](int kt, int buf) {
    const bf16* At = A + brow * K + kt * 64;
    const bf16* Bt = B + bcol * K + kt * 64;
#pragma unroll
    for (int i = 0; i < 4; ++i) {
      const int ch = tid + i * 512;
      const int row = ch >> 3;
      const int j = (ch & 7) ^ (row & 7);
      gld_lds16(At + (size_t)row * K + j * 8, &Al[buf][(wid * 64 + i * 512) * 8]);
    }
#pragma unroll
    for (int i = 0; i < 4; ++i) {
      const int ch = tid + i * 512;
      const int row = ch >> 3;
      const int j = (ch & 7) ^ (row & 7);
      gld_lds16(Bt + (size_t)row * K + j * 8, &Bl[buf][(wid * 64 + i * 512) * 8]);
    }
  };

  f32x4 acc0[4][4], acc1[4][4];
#pragma unroll
  for (int m = 0; m < 4; ++m)
#pragma unroll
    for (int n = 0; n < 4; ++n) {
      acc0[m][n] = (f32x4){0.f, 0.f, 0.f, 0.f};
      acc1[m][n] = (f32x4){0.f, 0.f, 0.f, 0.f};
    }

  const int l15 = lane & 15;
  const int cp0 = ((lane >> 4) ^ (lane & 7)) * 8;
  const int cp1 = ((4 + (lane >> 4)) ^ (lane & 7)) * 8;

  stage(0, 0);
  stage(1, 1);
  asm volatile("s_waitcnt vmcnt(8)" ::: "memory");
  __builtin_amdgcn_s_barrier();

  for (int kt = 0; kt < NT; ++kt) {
    const bf16* Ab = &Al[kt & 1][0];
    const bf16* Bb = &Bl[kt & 1][0];
    short8 bB[4][2], aA[4][2];
#pragma unroll
    for (int n = 0; n < 4; ++n) {
      const int rb = (wc * 64 + n * 16 + l15) * 64;
      bB[n][0] = *reinterpret_cast<const short8*>(&Bb[rb + cp0]);
      bB[n][1] = *reinterpret_cast<const short8*>(&Bb[rb + cp1]);
    }
#pragma unroll
    for (int m = 0; m < 4; ++m) {
      const int ra = (wr * 128 + m * 16 + l15) * 64;
      aA[m][0] = *reinterpret_cast<const short8*>(&Ab[ra + cp0]);
      aA[m][1] = *reinterpret_cast<const short8*>(&Ab[ra + cp1]);
    }
    __builtin_amdgcn_s_setprio(1);
#pragma unroll
    for (int m = 0; m < 4; ++m)
#pragma unroll
      for (int n = 0; n < 4; ++n) {
        acc0[m][n] = __builtin_amdgcn_mfma_f32_16x16x32_bf16(aA[m][0], bB[n][0],
                                                             acc0[m][n], 0, 0, 0);
        acc0[m][n] = __builtin_amdgcn_mfma_f32_16x16x32_bf16(aA[m][1], bB[n][1],
                                                             acc0[m][n], 0, 0, 0);
      }
    __builtin_amdgcn_s_setprio(0);
#pragma unroll
    for (int m = 0; m < 4; ++m) {
      const int ra = (wr * 128 + 64 + m * 16 + l15) * 64;
      aA[m][0] = *reinterpret_cast<const short8*>(&Ab[ra + cp0]);
      aA[m][1] = *reinterpret_cast<const short8*>(&Ab[ra + cp1]);
    }
    __builtin_amdgcn_s_setprio(1);
#pragma unroll
    for (int m = 0; m < 4; ++m)
#pragma unroll
      for (int n = 0; n < 4; ++n) {
        acc1[m][n] = __builtin_amdgcn_mfma_f32_16x16x32_bf16(aA[m][0], bB[n][0],
                                                             acc1[m][n], 0, 0, 0);
        acc1[m][n] = __builtin_amdgcn_mfma_f32_16x16x32_bf16(aA[m][1], bB[n][1],
                                                             acc1[m][n], 0, 0, 0);
      }
    __builtin_amdgcn_s_setprio(0);

    if (kt + 1 < NT) {
      __builtin_amdgcn_s_barrier();
      if (kt + 2 < NT) {
        stage(kt + 2, kt & 1);
        asm volatile("s_waitcnt vmcnt(8)" ::: "memory");
      } else {
        asm volatile("s_waitcnt vmcnt(0)" ::: "memory");
      }
      __builtin_amdgcn_s_barrier();
    }
  }

#pragma unroll
  for (int mh = 0; mh < 2; ++mh) {
#pragma unroll
    for (int m = 0; m < 4; ++m) {
      const long r0 = brow + wr * 128 + mh * 64 + m * 16 + (lane >> 4) * 4;
#pragma unroll
      for (int n = 0; n < 4; ++n) {
        const long c0 = bcol + wc * 64 + n * 16 + l15;
        const f32x4 v = mh ? acc1[m][n] : acc0[m][n];
#pragma unroll
        for (int r = 0; r < 4; ++r) {
          if constexpr (sizeof(OutT) == 2)
            C[(r0 + r) * N + c0] = __float2bfloat16(v[r]);
          else
            C[(r0 + r) * N + c0] = v[r];
        }
      }
    }
  }
}

// ------- 256x128-tile bf16 GEMM (out-proj), counted-vmcnt pipeline ---------
__global__ __launch_bounds__(512, 1) void k_gemm_op(
    const bf16* __restrict__ A, const bf16* __restrict__ B,
    float* __restrict__ C, int M, int N, int K) {
  __shared__ bf16 Al[2][256 * 64];   // 64 KB
  __shared__ bf16 Bl[2][128 * 64];   // 32 KB
  const int tid = threadIdx.x;
  const int lane = tid & 63;
  const int wid = tid >> 6;
  const int wr = wid >> 1;
  const int wc = wid & 1;
  const int2 bxy = xcd_swz(gridDim.x);
  const long brow = (long)bxy.y * 256;
  const long bcol = (long)bxy.x * 128;
  const int NT = K >> 6;

  auto stage = [&](int kt, int buf) {
    const bf16* At = A + brow * K + kt * 64;
    const bf16* Bt = B + bcol * K + kt * 64;
#pragma unroll
    for (int i = 0; i < 4; ++i) {
      const int ch = tid + i * 512;
      const int row = ch >> 3;
      const int j = (ch & 7) ^ (row & 7);
      gld_lds16(At + (size_t)row * K + j * 8, &Al[buf][(wid * 64 + i * 512) * 8]);
    }
#pragma unroll
    for (int i = 0; i < 2; ++i) {
      const int ch = tid + i * 512;
      const int row = ch >> 3;
      const int j = (ch & 7) ^ (row & 7);
      gld_lds16(Bt + (size_t)row * K + j * 8, &Bl[buf][(wid * 64 + i * 512) * 8]);
    }
  };

  f32x4 acc[4][4];
#pragma unroll
  for (int m = 0; m < 4; ++m)
#pragma unroll
    for (int n = 0; n < 4; ++n) acc[m][n] = (f32x4){0.f, 0.f, 0.f, 0.f};

  const int l15 = lane & 15;
  const int cp0 = ((lane >> 4) ^ (lane & 7)) * 8;
  const int cp1 = ((4 + (lane >> 4)) ^ (lane & 7)) * 8;

  stage(0, 0);
  stage(1, 1);
  asm volatile("s_waitcnt vmcnt(6)" ::: "memory");
  __builtin_amdgcn_s_barrier();

  for (int kt = 0; kt < NT; ++kt) {
    const bf16* Ab = &Al[kt & 1][0];
    const bf16* Bb = &Bl[kt & 1][0];
    short8 bB[4][2], aA[4][2];
#pragma unroll
    for (int n = 0; n < 4; ++n) {
      const int rb = (wc * 64 + n * 16 + l15) * 64;
      bB[n][0] = *reinterpret_cast<const short8*>(&Bb[rb + cp0]);
      bB[n][1] = *reinterpret_cast<const short8*>(&Bb[rb + cp1]);
    }
#pragma unroll
    for (int m = 0; m < 4; ++m) {
      const int ra = (wr * 64 + m * 16 + l15) * 64;
      aA[m][0] = *reinterpret_cast<const short8*>(&Ab[ra + cp0]);
      aA[m][1] = *reinterpret_cast<const short8*>(&Ab[ra + cp1]);
    }
    __builtin_amdgcn_s_setprio(1);
#pragma unroll
    for (int m = 0; m < 4; ++m)
#pragma unroll
      for (int n = 0; n < 4; ++n) {
        acc[m][n] = __builtin_amdgcn_mfma_f32_16x16x32_bf16(aA[m][0], bB[n][0],
                                                            acc[m][n], 0, 0, 0);
        acc[m][n] = __builtin_amdgcn_mfma_f32_16x16x32_bf16(aA[m][1], bB[n][1],
                                                            acc[m][n], 0, 0, 0);
      }
    __builtin_amdgcn_s_setprio(0);

    if (kt + 1 < NT) {
      __builtin_amdgcn_s_barrier();
      if (kt + 2 < NT) {
        stage(kt + 2, kt & 1);
        asm volatile("s_waitcnt vmcnt(6)" ::: "memory");
      } else {
        asm volatile("s_waitcnt vmcnt(0)" ::: "memory");
      }
      __builtin_amdgcn_s_barrier();
    }
  }

#pragma unroll
  for (int m = 0; m < 4; ++m) {
    const long r0 = brow + wr * 64 + m * 16 + (lane >> 4) * 4;
#pragma unroll
    for (int n = 0; n < 4; ++n) {
      const long c0 = bcol + wc * 64 + n * 16 + l15;
#pragma unroll
      for (int r = 0; r < 4; ++r) C[(r0 + r) * N + c0] = acc[m][n][r];
    }
  }
}

// ---------------- RMSNorm + RoPE + layout for attention ----------------
__global__ __launch_bounds__(256) void k_normrope(
    const bf16* __restrict__ QKVb, const float* __restrict__ cosb,
    const float* __restrict__ sinb, const float* __restrict__ qw,
    const float* __restrict__ kw, bf16* __restrict__ Qb, bf16* __restrict__ Kb,
    bf16* __restrict__ Vb) {
  const int lane = threadIdx.x & 63;
  const int row = blockIdx.x * 4 + (threadIdx.x >> 6);
  const int s = row >> 5;
  const int idx = row & 31;
  const bf16* src = QKVb + (size_t)s * 4096 + idx * 128;
  float x0 = __bfloat162float(src[lane]);
  float x1 = __bfloat162float(src[lane + 64]);
  if (idx < 24) {
    float ss = x0 * x0 + x1 * x1;
#pragma unroll
    for (int off = 1; off < 64; off <<= 1) ss += __shfl_xor(ss, off);
    const float rn = rsqrtf(ss * (1.f / 128.f) + 1e-6f);
    const float* w = (idx < 16) ? qw : kw;
    x0 = x0 * rn * w[lane];
    x1 = x1 * rn * w[lane + 64];
    const float c0 = cosb[(size_t)s * 128 + lane];
    const float c1 = cosb[(size_t)s * 128 + lane + 64];
    const float s0 = sinb[(size_t)s * 128 + lane];
    const float s1 = sinb[(size_t)s * 128 + lane + 64];
    float o0 = x0 * c0 - x1 * s0;
    float o1 = x1 * c1 + x0 * s1;
    if (idx < 16) { o0 *= QSCALE; o1 *= QSCALE; }
    bf16* dst = (idx < 16) ? (Qb + ((size_t)idx * S_LEN + s) * 128)
                           : (Kb + ((size_t)(idx - 16) * S_LEN + s) * 128);
    dst[lane] = __float2bfloat16(o0);
    dst[lane + 64] = __float2bfloat16(o1);
  } else {
    bf16* dst = Vb + ((size_t)(idx - 24) * S_LEN + s) * 128;
    dst[lane] = __float2bfloat16(x0);
    dst[lane + 64] = __float2bfloat16(x1);
  }
}

// ---------------- V transpose: Vb [KV][S][128] -> Vt [KV][128][S] ----------
__global__ __launch_bounds__(256) void k_vt(const bf16* __restrict__ Vb,
                                            bf16* __restrict__ Vt) {
  __shared__ bf16 Lds[64][136];
  const int tid = threadIdx.x;
  const int s0 = blockIdx.x * 64;
  const int kv = blockIdx.y;
#pragma unroll
  for (int pass = 0; pass < 4; ++pass) {
    const int c = tid + pass * 256;
    const int r = c >> 4;
    const int off = (c & 15) * 8;
    *reinterpret_cast<short8*>(&Lds[r][off]) =
        *reinterpret_cast<const short8*>(
            &Vb[((size_t)kv * S_LEN + s0 + r) * 128 + off]);
  }
  __syncthreads();
#pragma unroll
  for (int pass = 0; pass < 4; ++pass) {
    const int c = tid + pass * 256;
    const int d = c >> 3;
    const int so = (c & 7) * 8;
    short8 o;
#pragma unroll
    for (int j = 0; j < 8; ++j) {
      bf16 e = Lds[so + j][d];
      o[j] = *reinterpret_cast<short*>(&e);
    }
    *reinterpret_cast<short8*>(&Vt[((size_t)kv * 128 + d) * S_LEN + s0 + so]) = o;
  }
}

// ---------------- causal flash attention (GQA 16q/8kv, D=128) ----------------
// R11 structure: paired grid, K+V LDS dbuf via gld_lds, swapped QK^T (lane
// owns one q-row), P via cvt_pk -> b32 LDS, lane-local softmax.
__global__ __launch_bounds__(256) void k_attn(const bf16* __restrict__ Qb,
                                              const bf16* __restrict__ Kb,
                                              const bf16* __restrict__ Vt_g,
                                              bf16* __restrict__ AO) {
  __shared__ bf16 Kl[2][64 * 128];   // [kv][d], chunk-swizzled, linear
  __shared__ bf16 Vl[2][128 * 64];   // [d][kv], chunk-swizzled, linear
  __shared__ bf16 Pl[4][16 * 64];    // P[q][kv], chunk-swizzled  (8 KB)
  const int tid = threadIdx.x;
  const int lane = tid & 63;
  const int wv = tid >> 6;
  const int h = blockIdx.y;
  const int kvh = h >> 1;
  const int c16 = lane & 15;
  const int hi = lane >> 4;
  const int kk = hi * 8;

  const bf16* Kbase = Kb + (size_t)kvh * S_LEN * 128;
  const bf16* Vbase = Vt_g + (size_t)kvh * 128 * S_LEN;

  auto stage = [&](int t, int buf) {
    const bf16* Kt = Kbase + (size_t)t * 64 * 128;
    const bf16* Vt = Vbase + t * 64;
#pragma unroll
    for (int p = 0; p < 4; ++p) {
      const int ch = tid + p * 256;
      const int row = ch >> 4, cp = ch & 15;
      const int c = (cp & 8) | ((cp & 7) ^ (row & 7));
      gld_lds16(Kt + row * 128 + c * 8, &Kl[buf][(wv * 64 + p * 256) * 8]);
    }
#pragma unroll
    for (int p = 0; p < 4; ++p) {
      const int ch = tid + p * 256;
      const int d = ch >> 3, cp = ch & 7;
      const int c = cp ^ (d & 7);
      gld_lds16(Vt + (size_t)d * S_LEN + c * 8, &Vl[buf][(wv * 64 + p * 256) * 8]);
    }
  };

  for (int half = 0; half < 2; ++half) {
    const int qt = half ? (63 - blockIdx.x) : blockIdx.x;
    const int qrow = qt * 64 + wv * 16;
    const int grow = qrow + c16;        // this lane's global q row

    __syncthreads();
    stage(0, 0);

    short8 qf[4];
    {
      const bf16* qp = Qb + ((size_t)h * S_LEN + grow) * 128 + kk;
#pragma unroll
      for (int ks = 0; ks < 4; ++ks)
        qf[ks] = *reinterpret_cast<const short8*>(qp + ks * 32);
    }

    f32x4 oacc[8];
#pragma unroll
    for (int i = 0; i < 8; ++i) oacc[i] = (f32x4){0.f, 0.f, 0.f, 0.f};
    float m_run = -1e30f;
    float l_part = 0.f;

    auto tile = [&](int t, int buf, bool mask) {
      // S^T = K Q^T: sacc[nt] reg r -> kv = t*64 + nt*16 + 4*hi + r, q = c16
      f32x4 sacc[4];
#pragma unroll
      for (int nt = 0; nt < 4; ++nt) sacc[nt] = (f32x4){0.f, 0.f, 0.f, 0.f};
#pragma unroll
      for (int ks = 0; ks < 4; ++ks) {
#pragma unroll
        for (int nt = 0; nt < 4; ++nt) {
          const int row = nt * 16 + c16;
          const int ck = ks * 4 + hi;
          const int ckp = (ck & 8) | ((ck & 7) ^ (row & 7));
          short8 kf =
              *reinterpret_cast<const short8*>(&Kl[buf][row * 128 + ckp * 8]);
          sacc[nt] = __builtin_amdgcn_mfma_f32_16x16x32_bf16(kf, qf[ks],
                                                             sacc[nt], 0, 0, 0);
        }
      }

      // lane-local softmax (q = c16): mask + max tree + 2 shfl reduce
      float tm = -1e30f;
#pragma unroll
      for (int nt = 0; nt < 4; ++nt)
#pragma unroll
        for (int r = 0; r < 4; ++r) {
          float sv = sacc[nt][r];
          if (mask && (t * 64 + nt * 16 + 4 * hi + r > grow)) sv = -1e30f;
          sacc[nt][r] = sv;
          tm = fmaxf(tm, sv);
        }
      tm = fmaxf(tm, __shfl_xor(tm, 16));
      tm = fmaxf(tm, __shfl_xor(tm, 32));
      if (__any(tm > m_run + 8.f)) {
        const float mn = fmaxf(m_run, tm);
        const float alpha = fexp2(m_run - mn);
        m_run = mn;
        l_part *= alpha;
#pragma unroll
        for (int dn = 0; dn < 8; ++dn) oacc[dn] *= alpha;
      }

      // exp + pack pairs + write P (b32, chunk-swizzled by q&7)
#pragma unroll
      for (int nt = 0; nt < 4; ++nt) {
        const float p0 = fexp2(sacc[nt][0] - m_run);
        const float p1 = fexp2(sacc[nt][1] - m_run);
        const float p2 = fexp2(sacc[nt][2] - m_run);
        const float p3 = fexp2(sacc[nt][3] - m_run);
        l_part += (p0 + p1) + (p2 + p3);
        const unsigned w0 = cvtpk_bf16(p0, p1);
        const unsigned w1 = cvtpk_bf16(p2, p3);
        const int chunk = (2 * nt + (hi >> 1)) ^ (c16 & 7);
        const int base = c16 * 64 + chunk * 8 + 4 * (hi & 1);
        *reinterpret_cast<unsigned*>(&Pl[wv][base]) = w0;
        *reinterpret_cast<unsigned*>(&Pl[wv][base + 2]) = w1;
      }

      // O^T += V^T P^T: oacc[dn] reg r -> d = dn*16 + 4*hi + r, q = c16
#pragma unroll
      for (int ks = 0; ks < 2; ++ks) {
        const int pc = (ks * 4 + hi) ^ (c16 & 7);
        short8 pf =
            *reinterpret_cast<const short8*>(&Pl[wv][c16 * 64 + pc * 8]);
#pragma unroll
        for (int dn = 0; dn < 8; ++dn) {
          const int d = dn * 16 + c16;
          const int cvp = (ks * 4 + hi) ^ (d & 7);
          short8 vf =
              *reinterpret_cast<const short8*>(&Vl[buf][d * 64 + cvp * 8]);
          oacc[dn] =
              __builtin_amdgcn_mfma_f32_16x16x32_bf16(vf, pf, oacc[dn], 0, 0, 0);
        }
      }
    };

    __syncthreads();  // tile 0 staged
    int cur = 0;
    for (int t = 0; t < qt; ++t) {
      stage(t + 1, cur ^ 1);
      tile(t, cur, false);
      __syncthreads();
      cur ^= 1;
    }
    tile(qt, cur, true);

    // epilogue: reduce l across kv-slot groups, write O (pair-packed b32)
    float lt = l_part;
    lt += __shfl_xor(lt, 16);
    lt += __shfl_xor(lt, 32);
    const float inv = 1.f / lt;
    bf16* dst = AO + (size_t)grow * HID_DIM + h * 128;
#pragma unroll
    for (int dn = 0; dn < 8; ++dn) {
#pragma unroll
      for (int w = 0; w < 2; ++w) {
        const unsigned pk = cvtpk_bf16(oacc[dn][2 * w] * inv,
                                       oacc[dn][2 * w + 1] * inv);
        *reinterpret_cast<unsigned*>(&dst[dn * 16 + 4 * hi + 2 * w]) = pk;
      }
    }
  }
}

extern "C" void kernel_launch(void* const* d_in, const int* in_sizes, int n_in,
                              void* d_out, int out_size, void* d_ws,
                              size_t ws_size, hipStream_t stream) {
  (void)in_sizes; (void)n_in; (void)out_size; (void)ws_size;
  const float* hs = (const float*)d_in[0];
  const float* cosb = (const float*)d_in[1];
  const float* sinb = (const float*)d_in[2];
  const float* wq = (const float*)d_in[3];
  const float* wk = (const float*)d_in[4];
  const float* wv = (const float*)d_in[5];
  const float* wo = (const float*)d_in[6];
  const float* qnw = (const float*)d_in[7];
  const float* knw = (const float*)d_in[8];
  float* out = (float*)d_out;
  char* ws = (char*)d_ws;

  bf16* Ah = (bf16*)(ws + 0);              // hidden bf16        16.78 MB
  bf16* Wqkv = (bf16*)(ws + 16777216);     // packed qkv weights 16.78 MB
  bf16* Wo = (bf16*)(ws + 33554432);       // wo bf16             8.39 MB
  bf16* QKVb = (bf16*)(ws + 41943040);     // qkv proj bf16      33.55 MB
  bf16* Qb = (bf16*)(ws + 75497472);       // Q [H][S][D]        16.78 MB
  bf16* Kb = (bf16*)(ws + 92274688);       // K [KV][S][D]        8.39 MB
  bf16* Vb = (bf16*)(ws + 100663296);      // V [KV][S][D]        8.39 MB
  bf16* AO = (bf16*)(ws + 109051904);      // attn out [S][H*D]  16.78 MB
  bf16* Vt = (bf16*)(ws + 125829120);      // V^T [KV][128][S]    8.39 MB

  k_cvt5<<<dim3(10240), dim3(256), 0, stream>>>(hs, wq, wk, wv, wo, Ah, Wqkv,
                                                Wo);
  k_gemm256<bf16><<<dim3(16, 16), dim3(512), 0, stream>>>(Ah, Wqkv, QKVb, 4096,
                                                          4096, 2048);
  k_normrope<<<dim3(32768), dim3(256), 0, stream>>>(QKVb, cosb, sinb, qnw, knw,
                                                    Qb, Kb, Vb);
  k_vt<<<dim3(64, 8), dim3(256), 0, stream>>>(Vb, Vt);
  k_attn<<<dim3(32, 16), dim3(256), 0, stream>>>(Qb, Kb, Vt, AO);
  k_gemm_op<<<dim3(16, 16), dim3(512), 0, stream>>>(AO, Wo, out, 4096, 2048,
                                                    2048);
}